// Round 19
// baseline (79.244 us; speedup 1.0000x reference)
//
#include <hip/hip_runtime.h>
#include <hip/hip_bf16.h>

#define B_    8
#define CIN_  256
#define CC_   128
#define COUT_ 64
#define HP_   68            // f padded: 64 + 2 + 2
#define HPX_  (HP_ * HP_)   // 4624
#define XQW_  66            // x padded: 64 + 1 + 1
#define XQPX_ (XQW_ * XQW_) // 4356

typedef __attribute__((ext_vector_type(8))) short bh8;
typedef __attribute__((ext_vector_type(4))) float f4;

__device__ __forceinline__ ushort f2bf(float f) {   // RNE
    uint u = __float_as_uint(f);
    return (ushort)((u + 0x7fffu + ((u >> 16) & 1u)) >> 16);
}
__device__ __forceinline__ float bf2f(ushort s) {
    return __uint_as_float(((uint)s) << 16);
}
__device__ __forceinline__ short f2bf_c(float f) {
    __hip_bfloat16 h = __float2bfloat16(f);
    short s;
    __builtin_memcpy(&s, &h, 2);
    return s;
}

// async 16B global -> LDS DMA (dst linear: wave-uniform base + lane*16)
__device__ __forceinline__ void gload16(const short* g, short* l) {
    __builtin_amdgcn_global_load_lds(
        (const __attribute__((address_space(1))) void*)g,
        (__attribute__((address_space(3))) void*)l, 16, 0, 0);
}

// ---- merged prep: ring-zero + weight transforms + x transpose/quantize
// Weights stored PRE-SWIZZLED so linear global_load_lds reproduces the
// slot-swizzled LDS layout the compute loops read (m173 pattern).
#define NB_MISC 2217
__global__ __launch_bounds__(256) void prep_all(const float* __restrict__ x,
                                                const float* __restrict__ w_ext,
                                                const float* __restrict__ w_reg,
                                                short* __restrict__ wg,
                                                short* __restrict__ wa,
                                                ushort* __restrict__ fpad_t,
                                                ushort* __restrict__ xq) {
    __shared__ float xt[2][32][65];
    const int tid = threadIdx.x;
    if (blockIdx.x < NB_MISC) {
        int e = blockIdx.x * 256 + tid;
        if (e < 67584) {
            int seg = e & 15;
            int t = e >> 4;
            int b = t / 528, rp = t - b * 528;
            int i, j;
            if (rp < 136) { i = rp / 68; j = rp - (rp / 68) * 68; }
            else if (rp < 272) { int r = rp - 136; i = 66 + r / 68; j = r - (r / 68) * 68; }
            else { int r = rp - 272; i = 2 + (r >> 2); int c = r & 3; j = (c < 2) ? c : c + 64; }
            uint4 z; z.x = 0u; z.y = 0u; z.z = 0u; z.w = 0u;
            *(uint4*)&fpad_t[(((size_t)b * HPX_) + i * HP_ + j) * 128 + seg * 8] = z;
            return;
        }
        e -= 67584;
        if (e < 294912) {
            int ci = e & 31;
            int t  = e >> 5;
            int cc = t & 127;
            int t2 = t >> 7;
            int rs = t2 % 9, cb = t2 / 9;
            // pre-swizzled index: phase p = cb*3 + rs/3, s = rs%3
            int p = cb * 3 + rs / 3, s = rs % 3;
            int kgc = ci >> 3, j = ci & 7;
            int idx = p * 12288 + s * 4096 + cc * 32 + ((((cc >> 1) + kgc) & 3) << 3) + j;
            wg[idx] = (short)f2bf(w_ext[(cc * CIN_ + cb * 32 + ci) * 9 + rs]);
            return;
        }
        e -= 294912;
        if (e < 204800) {
            int ci = e & 31;
            int o  = (e >> 5) & 63;
            int rest = e >> 11;
            int k = rest % 25, q = rest / 25;
            // pre-swizzled index: phase p = q*5 + k/5, v = k%5
            int p = q * 5 + k / 5, v = k % 5;
            int kgc = ci >> 3, j = ci & 7;
            int idx = p * 10240 + v * 2048 + o * 32 + ((((o >> 1) + kgc) & 3) << 3) + j;
            wa[idx] = (short)f2bf(w_reg[(o * CC_ + q * 32 + ci) * 25 + k]);
        }
        return;
    }

    const int pid = blockIdx.x - NB_MISC;
    const int rp = pid % 33, cb = (pid / 33) & 7, b = pid / 264;

#pragma unroll
    for (int rr = 0; rr < 2; ++rr) {
        int y = rp * 2 + rr - 1;
        if ((unsigned)y < 64u) {
            int xx = tid & 63, wv = tid >> 6;
#pragma unroll
            for (int it = 0; it < 8; ++it) {
                int ci = it * 4 + wv;
                xt[rr][ci][xx] = x[(((size_t)(b * CIN_ + cb * 32 + ci)) * 64 + y) * 64 + xx];
            }
        }
    }
    __syncthreads();

    for (int e = tid; e < 528; e += 256) {
        int rr = e / 264, t = e - rr * 264;
        int hc = t >> 2, seg = t & 3;
        int y = rp * 2 + rr - 1, xx = hc - 1;
        uint pk[4] = {0u, 0u, 0u, 0u};
        if ((unsigned)y < 64u && (unsigned)xx < 64u) {
#pragma unroll
            for (int i = 0; i < 4; ++i) {
                uint lo = f2bf(xt[rr][seg * 8 + i * 2][xx]);
                uint hi = f2bf(xt[rr][seg * 8 + i * 2 + 1][xx]);
                pk[i] = lo | (hi << 16);
            }
        }
        uint4 v; v.x = pk[0]; v.y = pk[1]; v.z = pk[2]; v.w = pk[3];
        *(uint4*)&xq[((((size_t)(b * 8 + cb)) * XQPX_) + (rp * 2 + rr) * XQW_ + hc) * 32 + seg * 8] = v;
    }
}

// ---- conv 3x3 bf16 MFMA; 8x8 tile, 256 thr / 4 waves; weights via async
// global_load_lds DMA (24 calls/phase, 6 per wave), x tile reg-staged.
__global__ __launch_bounds__(256)
__attribute__((amdgpu_waves_per_eu(2, 2)))
void conv3x3_mfma(const ushort* __restrict__ xq,
                  const short* __restrict__ wg,
                  const float* __restrict__ bext,
                  ushort* __restrict__ fpad_t) {
    __shared__ __align__(16) short xh[2][100 * 72];
    __shared__ __align__(16) short wlds[2][3 * 128 * 32];
    const int tid = threadIdx.x;
    const int lane = tid & 63, wv = tid >> 6;
    const int j0 = blockIdx.x * 8, i0 = blockIdx.y * 8, b = blockIdx.z;
    const int l15 = lane & 15, kg = lane >> 4;
    const int cc0 = wv * 32;

    int abase[2];
#pragma unroll
    for (int mm = 0; mm < 2; ++mm) {
        int cc = cc0 + mm * 16 + l15;
        abase[mm] = cc * 32 + ((((cc >> 1) + kg) & 3) << 3);
    }
    int xb[4];
#pragma unroll
    for (int nn = 0; nn < 4; ++nn) {
        int px = nn * 16 + l15, pi = px >> 3, pj = px & 7;
        xb[nn] = (pi * 10 + pj) * 72 + kg * 8;
    }
    const int hp0 = tid >> 2, seg0 = tid & 3;
    const int hr0 = hp0 / 10, hc0 = hp0 - hr0 * 10;
    const int xsrc0 = ((i0 + hr0) * XQW_ + (j0 + hc0)) * 32 + seg0 * 8;
    const int xdst0 = hp0 * 72 + seg0 * 8;
    const int hp1 = (tid + 256) >> 2;
    const int hr1 = hp1 / 10, hc1 = hp1 - hr1 * 10;
    const int xsrc1 = ((i0 + hr1) * XQW_ + (j0 + hc1)) * 32 + seg0 * 8;
    const int xdst1 = hp1 * 72 + seg0 * 8;
    const bool x1ok = tid < 144;

    f4 acc[2][4] = {};

    // prologue: DMA w phase 0 + reg-stage x cb 0
    {
#pragma unroll
        for (int n = 0; n < 6; ++n) {
            int c = (wv * 6 + n) * 64;   // chunk base for this call
            gload16(wg + (size_t)c * 8 + lane * 8, &wlds[0][c * 8]);
        }
        const ushort* xbase = xq + (((size_t)(b * 8 + 0)) * XQPX_) * 32;
        *(bh8*)&xh[0][xdst0] = *(const bh8*)&xbase[xsrc0];
        if (x1ok) *(bh8*)&xh[0][xdst1] = *(const bh8*)&xbase[xsrc1];
    }
    __syncthreads();

    int p = 0;
#pragma unroll 1
    for (int cb = 0; cb < 8; ++cb) {
        const int xbuf = cb & 1;
#pragma unroll 1
        for (int g = 0; g < 3; ++g) {
            const int buf = p & 1;
            const bool wmore = (p < 23);
            const bool xmore = (g == 2) && (cb < 7);

            // 1. issue next-phase weight DMA (async, lands in buf^1)
            if (wmore) {
                const short* gsrc = wg + (size_t)(p + 1) * 12288;
#pragma unroll
                for (int n = 0; n < 6; ++n) {
                    int c = (wv * 6 + n) * 64;
                    gload16(gsrc + (size_t)c * 8 + lane * 8, &wlds[buf ^ 1][c * 8]);
                }
            }
            bh8 xr0, xr1;
            if (xmore) {
                const ushort* xbase = xq + (((size_t)(b * 8 + cb + 1)) * XQPX_) * 32;
                xr0 = *(const bh8*)&xbase[xsrc0];
                if (x1ok) xr1 = *(const bh8*)&xbase[xsrc1];
            }

            // 2. compute 3 s-steps from LDS only
            const short* wb = wlds[buf];
            const int goffs = g * 10 * 72;
#pragma unroll
            for (int s = 0; s < 3; ++s) {
                bh8 a[2], bb[4];
#pragma unroll
                for (int mm = 0; mm < 2; ++mm)
                    a[mm] = *(const bh8*)&wb[s * 4096 + abase[mm]];
#pragma unroll
                for (int nn = 0; nn < 4; ++nn)
                    bb[nn] = *(const bh8*)&xh[xbuf][xb[nn] + goffs + s * 72];
#pragma unroll
                for (int mm = 0; mm < 2; ++mm)
#pragma unroll
                    for (int nn = 0; nn < 4; ++nn)
                        acc[mm][nn] = __builtin_amdgcn_mfma_f32_16x16x32_bf16(
                            a[mm], bb[nn], acc[mm][nn], 0, 0, 0);
            }

            // 3. write-late x tile
            if (xmore) {
                *(bh8*)&xh[xbuf ^ 1][xdst0] = xr0;
                if (x1ok) *(bh8*)&xh[xbuf ^ 1][xdst1] = xr1;
            }
            __syncthreads();
            ++p;
        }
    }

#pragma unroll
    for (int mm = 0; mm < 2; ++mm) {
        const int ccb = cc0 + mm * 16 + kg * 4;
        float bv0 = bext[ccb + 0], bv1 = bext[ccb + 1];
        float bv2 = bext[ccb + 2], bv3 = bext[ccb + 3];
#pragma unroll
        for (int nn = 0; nn < 4; ++nn) {
            int px = nn * 16 + l15, pi = px >> 3, pj = px & 7;
            size_t row = (size_t)b * HPX_ + (2 + i0 + pi) * HP_ + (2 + j0 + pj);
            uint lo = (uint)f2bf(acc[mm][nn][0] + bv0) | ((uint)f2bf(acc[mm][nn][1] + bv1) << 16);
            uint hi = (uint)f2bf(acc[mm][nn][2] + bv2) | ((uint)f2bf(acc[mm][nn][3] + bv3) << 16);
            uint2 pk; pk.x = lo; pk.y = hi;
            *(uint2*)&fpad_t[row * 128 + ccb] = pk;
        }
    }
}

// ---- autocorr bf16 MFMA; 128-px blocks (16x8), 512 thr / 8 waves (2oh x 4pxg);
// full-K in block, direct store; weights via async global_load_lds DMA
// (20 calls/phase, n%8 per wave).
__global__ __launch_bounds__(512)
__attribute__((amdgpu_waves_per_eu(2, 2)))
void autocorr_mfma(const ushort* __restrict__ ft,
                   const short* __restrict__ wA,
                   const float* __restrict__ breg,
                   float* __restrict__ out) {
    __shared__ __align__(16) short flds[240 * 136];      // 12 x 20 halo px, 65.3 KB
    __shared__ __align__(16) short wlds[2][5 * 64 * 32]; // 41.0 KB
    const int tid = threadIdx.x;
    const int lane = tid & 63, wv = tid >> 6;
    const int oh = wv >> 2, pxg = wv & 3;
    const int j0 = blockIdx.x * 16, i0 = blockIdx.y * 8, b = blockIdx.z;
    const int l15 = lane & 15, kg = lane >> 4;

    int abase[2];
#pragma unroll
    for (int mm = 0; mm < 2; ++mm) {
        int o = oh * 32 + mm * 16 + l15;
        abase[mm] = o * 32 + ((((o >> 1) + kg) & 3) << 3);
    }

    // prologue: f-tile (240 hpx x 16 segs = 3840 chunks) + w phase 0 DMA
    for (int e = tid; e < 3840; e += 512) {
        int hp = e >> 4, seg = e & 15;
        int hr = hp / 20, hc = hp - hr * 20;
        const ushort* src = ft + ((size_t)b * HPX_ + (i0 + hr) * HP_ + (j0 + hc)) * 128 + seg * 8;
        *(bh8*)&flds[hp * 136 + seg * 8] = *(const bh8*)src;
    }
#pragma unroll 1
    for (int n = wv; n < 20; n += 8)
        gload16(wA + (size_t)n * 512 + lane * 8, &wlds[0][n * 512]);
    __syncthreads();

    f4 acc[2][2] = {};
    int base_off[2], cen_off[2];
#pragma unroll
    for (int t = 0; t < 2; ++t) {
        int px = pxg * 32 + t * 16 + l15;
        int pi = px >> 4, pj = px & 15;
        base_off[t] = (pi * 20 + pj) * 136 + kg * 8;
        cen_off[t]  = ((pi + 2) * 20 + (pj + 2)) * 136 + kg * 8;
    }

    int p = 0;
#pragma unroll 1
    for (int q = 0; q < 4; ++q) {
        float cen[2][8];
#pragma unroll
        for (int t = 0; t < 2; ++t) {
            bh8 c8 = *(const bh8*)&flds[cen_off[t] + q * 32];
#pragma unroll
            for (int jj = 0; jj < 8; ++jj) cen[t][jj] = bf2f((ushort)c8[jj]);
        }
#pragma unroll 1
        for (int u = 0; u < 5; ++u) {
            const int buf = p & 1;
            const bool wmore = (p < 19);

            // 1. issue next-phase weight DMA (async, lands in buf^1)
            if (wmore) {
                const short* gsrc = wA + (size_t)(p + 1) * 10240;
#pragma unroll 1
                for (int n = wv; n < 20; n += 8)
                    gload16(gsrc + (size_t)n * 512 + lane * 8, &wlds[buf ^ 1][n * 512]);
            }

            // 2. compute 5 v-steps from LDS only
            const short* wb = wlds[buf];
#pragma unroll
            for (int v = 0; v < 5; ++v) {
                const int koff = (u * 20 + v) * 136;
                bh8 a[2];
#pragma unroll
                for (int mm = 0; mm < 2; ++mm)
                    a[mm] = *(const bh8*)&wb[v * 2048 + abase[mm]];
                bh8 bb[2];
#pragma unroll
                for (int t = 0; t < 2; ++t) {
                    bh8 s8 = *(const bh8*)&flds[base_off[t] + q * 32 + koff];
#pragma unroll
                    for (int jj = 0; jj < 8; ++jj) {
                        float pr = bf2f((ushort)s8[jj]) * cen[t][jj];
                        bb[t][jj] = f2bf_c(pr);
                    }
                }
#pragma unroll
                for (int mm = 0; mm < 2; ++mm)
#pragma unroll
                    for (int t = 0; t < 2; ++t)
                        acc[mm][t] = __builtin_amdgcn_mfma_f32_16x16x32_bf16(
                            a[mm], bb[t], acc[mm][t], 0, 0, 0);
            }

            __syncthreads();
            ++p;
        }
    }

    // epilogue: D row -> o, col -> px (16-wide tile)
#pragma unroll
    for (int mm = 0; mm < 2; ++mm) {
#pragma unroll
        for (int reg = 0; reg < 4; ++reg) {
            int o = oh * 32 + mm * 16 + kg * 4 + reg;
            float bv = breg[o];
#pragma unroll
            for (int t = 0; t < 2; ++t) {
                int px = pxg * 32 + t * 16 + l15, pi = px >> 4, pj = px & 15;
                out[(((size_t)(b * COUT_ + o)) * 64 + i0 + pi) * 64 + j0 + pj] =
                    acc[mm][t][reg] + bv;
            }
        }
    }
}

extern "C" void kernel_launch(void* const* d_in, const int* in_sizes, int n_in,
                              void* d_out, int out_size, void* d_ws, size_t ws_size,
                              hipStream_t stream) {
    const float* x     = (const float*)d_in[0];
    const float* w_ext = (const float*)d_in[1];
    const float* b_ext = (const float*)d_in[2];
    const float* w_reg = (const float*)d_in[3];
    const float* b_reg = (const float*)d_in[4];
    float* out = (float*)d_out;

    char* ws = (char*)d_ws;
    const size_t FPADT_BYTES = (size_t)B_ * HPX_ * 128 * 2;
    const size_t WG_BYTES    = (size_t)8 * 9 * 128 * 32 * 2;
    const size_t WA_BYTES    = (size_t)4 * 25 * 64 * 32 * 2;
    ushort* fpad_t = (ushort*)ws;
    short*  wgq    = (short*)(ws + FPADT_BYTES);
    short*  wa     = (short*)(ws + FPADT_BYTES + WG_BYTES);
    ushort* xq     = (ushort*)(ws + FPADT_BYTES + WG_BYTES + WA_BYTES);

    prep_all<<<NB_MISC + 33 * 8 * 8, 256, 0, stream>>>(x, w_ext, w_reg, wgq, wa, fpad_t, xq);

    dim3 cgrid(8, 8, 8);
    conv3x3_mfma<<<cgrid, 256, 0, stream>>>(xq, wgq, b_ext, fpad_t);
    dim3 agrid(4, 8, 8);
    autocorr_mfma<<<agrid, 512, 0, stream>>>(fpad_t, wa, b_reg, out);
}

// Round 20
// 73.942 us; speedup vs baseline: 1.0717x; 1.0717x over previous
//
#include <hip/hip_runtime.h>
#include <hip/hip_bf16.h>

#define B_    8
#define CIN_  256
#define CC_   128
#define COUT_ 64
#define HP_   68            // f padded: 64 + 2 + 2
#define HPX_  (HP_ * HP_)   // 4624
#define XQW_  66            // x padded: 64 + 1 + 1
#define XQPX_ (XQW_ * XQW_) // 4356

typedef __attribute__((ext_vector_type(8))) short bh8;
typedef __attribute__((ext_vector_type(4))) float f4;

__device__ __forceinline__ ushort f2bf(float f) {   // RNE
    uint u = __float_as_uint(f);
    return (ushort)((u + 0x7fffu + ((u >> 16) & 1u)) >> 16);
}
__device__ __forceinline__ float bf2f(ushort s) {
    return __uint_as_float(((uint)s) << 16);
}
__device__ __forceinline__ short f2bf_c(float f) {
    __hip_bfloat16 h = __float2bfloat16(f);
    short s;
    __builtin_memcpy(&s, &h, 2);
    return s;
}

// ---- merged prep: ring-zero + weight transforms + x transpose/quantize
#define NB_MISC 2217
__global__ __launch_bounds__(256) void prep_all(const float* __restrict__ x,
                                                const float* __restrict__ w_ext,
                                                const float* __restrict__ w_reg,
                                                short* __restrict__ wg,
                                                short* __restrict__ wa,
                                                ushort* __restrict__ fpad_t,
                                                ushort* __restrict__ xq) {
    __shared__ float xt[2][32][65];
    const int tid = threadIdx.x;
    if (blockIdx.x < NB_MISC) {
        int e = blockIdx.x * 256 + tid;
        if (e < 67584) {
            int seg = e & 15;
            int t = e >> 4;
            int b = t / 528, rp = t - b * 528;
            int i, j;
            if (rp < 136) { i = rp / 68; j = rp - (rp / 68) * 68; }
            else if (rp < 272) { int r = rp - 136; i = 66 + r / 68; j = r - (r / 68) * 68; }
            else { int r = rp - 272; i = 2 + (r >> 2); int c = r & 3; j = (c < 2) ? c : c + 64; }
            uint4 z; z.x = 0u; z.y = 0u; z.z = 0u; z.w = 0u;
            *(uint4*)&fpad_t[(((size_t)b * HPX_) + i * HP_ + j) * 128 + seg * 8] = z;
            return;
        }
        e -= 67584;
        if (e < 294912) {
            int ci = e & 31;
            int t  = e >> 5;
            int cc = t & 127;
            int t2 = t >> 7;
            int rs = t2 % 9, cb = t2 / 9;
            wg[e] = (short)f2bf(w_ext[(cc * CIN_ + cb * 32 + ci) * 9 + rs]);
            return;
        }
        e -= 294912;
        if (e < 204800) {
            int ci = e & 31;
            int o  = (e >> 5) & 63;
            int rest = e >> 11;
            int k = rest % 25, q = rest / 25;
            wa[e] = (short)f2bf(w_reg[(o * CC_ + q * 32 + ci) * 25 + k]);
        }
        return;
    }

    const int pid = blockIdx.x - NB_MISC;
    const int rp = pid % 33, cb = (pid / 33) & 7, b = pid / 264;

#pragma unroll
    for (int rr = 0; rr < 2; ++rr) {
        int y = rp * 2 + rr - 1;
        if ((unsigned)y < 64u) {
            int xx = tid & 63, wv = tid >> 6;
#pragma unroll
            for (int it = 0; it < 8; ++it) {
                int ci = it * 4 + wv;
                xt[rr][ci][xx] = x[(((size_t)(b * CIN_ + cb * 32 + ci)) * 64 + y) * 64 + xx];
            }
        }
    }
    __syncthreads();

    for (int e = tid; e < 528; e += 256) {
        int rr = e / 264, t = e - rr * 264;
        int hc = t >> 2, seg = t & 3;
        int y = rp * 2 + rr - 1, xx = hc - 1;
        uint pk[4] = {0u, 0u, 0u, 0u};
        if ((unsigned)y < 64u && (unsigned)xx < 64u) {
#pragma unroll
            for (int i = 0; i < 4; ++i) {
                uint lo = f2bf(xt[rr][seg * 8 + i * 2][xx]);
                uint hi = f2bf(xt[rr][seg * 8 + i * 2 + 1][xx]);
                pk[i] = lo | (hi << 16);
            }
        }
        uint4 v; v.x = pk[0]; v.y = pk[1]; v.z = pk[2]; v.w = pk[3];
        *(uint4*)&xq[((((size_t)(b * 8 + cb)) * XQPX_) + (rp * 2 + rr) * XQW_ + hc) * 32 + seg * 8] = v;
    }
}

// ---- conv 3x3 bf16 MFMA; 8x8 tile, 256 thr / 4 waves, LDS-dbuf weight staging
// + T5 setprio around MFMA clusters (2 unsynced blocks/CU -> role diversity)
__global__ __launch_bounds__(256)
__attribute__((amdgpu_waves_per_eu(2, 2)))
void conv3x3_mfma(const ushort* __restrict__ xq,
                  const short* __restrict__ wg,
                  const float* __restrict__ bext,
                  ushort* __restrict__ fpad_t) {
    __shared__ __align__(16) short xh[2][100 * 72];
    __shared__ __align__(16) short wlds[2][3 * 128 * 32];
    const int tid = threadIdx.x;
    const int lane = tid & 63, wv = tid >> 6;
    const int j0 = blockIdx.x * 8, i0 = blockIdx.y * 8, b = blockIdx.z;
    const int l15 = lane & 15, kg = lane >> 4;
    const int cc0 = wv * 32;

    int abase[2];
#pragma unroll
    for (int mm = 0; mm < 2; ++mm) {
        int cc = cc0 + mm * 16 + l15;
        abase[mm] = cc * 32 + ((((cc >> 1) + kg) & 3) << 3);
    }
    int xb[4];
#pragma unroll
    for (int nn = 0; nn < 4; ++nn) {
        int px = nn * 16 + l15, pi = px >> 3, pj = px & 7;
        xb[nn] = (pi * 10 + pj) * 72 + kg * 8;
    }
    int wdst[6]; int goff[6];
#pragma unroll
    for (int k = 0; k < 6; ++k) {
        int c = tid + k * 256;
        int cc = (c & 511) >> 2, kgc = c & 3;
        wdst[k] = (c >> 9) * 4096 + cc * 32 + ((((cc >> 1) + kgc) & 3) << 3);
        goff[k] = c * 8;
    }
    const int hp0 = tid >> 2, seg0 = tid & 3;
    const int hr0 = hp0 / 10, hc0 = hp0 - hr0 * 10;
    const int xsrc0 = ((i0 + hr0) * XQW_ + (j0 + hc0)) * 32 + seg0 * 8;
    const int xdst0 = hp0 * 72 + seg0 * 8;
    const int hp1 = (tid + 256) >> 2;
    const int hr1 = hp1 / 10, hc1 = hp1 - hr1 * 10;
    const int xsrc1 = ((i0 + hr1) * XQW_ + (j0 + hc1)) * 32 + seg0 * 8;
    const int xdst1 = hp1 * 72 + seg0 * 8;
    const bool x1ok = tid < 144;

    f4 acc[2][4] = {};

    {
#pragma unroll
        for (int k = 0; k < 6; ++k)
            *(bh8*)&wlds[0][wdst[k]] = *(const bh8*)(wg + goff[k]);
        const ushort* xbase = xq + (((size_t)(b * 8 + 0)) * XQPX_) * 32;
        *(bh8*)&xh[0][xdst0] = *(const bh8*)&xbase[xsrc0];
        if (x1ok) *(bh8*)&xh[0][xdst1] = *(const bh8*)&xbase[xsrc1];
    }
    __syncthreads();

    int p = 0;
#pragma unroll 1
    for (int cb = 0; cb < 8; ++cb) {
        const int xbuf = cb & 1;
#pragma unroll 1
        for (int g = 0; g < 3; ++g) {
            const int buf = p & 1;
            const bool wmore = (p < 23);
            const bool xmore = (g == 2) && (cb < 7);

            bh8 wreg[6];
            const short* gsrc = wg + (size_t)(wmore ? (p + 1) : 23) * 12288;
#pragma unroll
            for (int k = 0; k < 6; ++k)
                wreg[k] = *(const bh8*)(gsrc + goff[k]);
            bh8 xr0, xr1;
            if (xmore) {
                const ushort* xbase = xq + (((size_t)(b * 8 + cb + 1)) * XQPX_) * 32;
                xr0 = *(const bh8*)&xbase[xsrc0];
                if (x1ok) xr1 = *(const bh8*)&xbase[xsrc1];
            }

            const short* wb = wlds[buf];
            const int goffs = g * 10 * 72;
#pragma unroll
            for (int s = 0; s < 3; ++s) {
                bh8 a[2], bb[4];
#pragma unroll
                for (int mm = 0; mm < 2; ++mm)
                    a[mm] = *(const bh8*)&wb[s * 4096 + abase[mm]];
#pragma unroll
                for (int nn = 0; nn < 4; ++nn)
                    bb[nn] = *(const bh8*)&xh[xbuf][xb[nn] + goffs + s * 72];
                __builtin_amdgcn_s_setprio(1);
#pragma unroll
                for (int mm = 0; mm < 2; ++mm)
#pragma unroll
                    for (int nn = 0; nn < 4; ++nn)
                        acc[mm][nn] = __builtin_amdgcn_mfma_f32_16x16x32_bf16(
                            a[mm], bb[nn], acc[mm][nn], 0, 0, 0);
                __builtin_amdgcn_s_setprio(0);
            }

            if (wmore) {
#pragma unroll
                for (int k = 0; k < 6; ++k)
                    *(bh8*)&wlds[buf ^ 1][wdst[k]] = wreg[k];
            }
            if (xmore) {
                *(bh8*)&xh[xbuf ^ 1][xdst0] = xr0;
                if (x1ok) *(bh8*)&xh[xbuf ^ 1][xdst1] = xr1;
            }
            __syncthreads();
            ++p;
        }
    }

#pragma unroll
    for (int mm = 0; mm < 2; ++mm) {
        const int ccb = cc0 + mm * 16 + kg * 4;
        float bv0 = bext[ccb + 0], bv1 = bext[ccb + 1];
        float bv2 = bext[ccb + 2], bv3 = bext[ccb + 3];
#pragma unroll
        for (int nn = 0; nn < 4; ++nn) {
            int px = nn * 16 + l15, pi = px >> 3, pj = px & 7;
            size_t row = (size_t)b * HPX_ + (2 + i0 + pi) * HP_ + (2 + j0 + pj);
            uint lo = (uint)f2bf(acc[mm][nn][0] + bv0) | ((uint)f2bf(acc[mm][nn][1] + bv1) << 16);
            uint hi = (uint)f2bf(acc[mm][nn][2] + bv2) | ((uint)f2bf(acc[mm][nn][3] + bv3) << 16);
            uint2 pk; pk.x = lo; pk.y = hi;
            *(uint2*)&fpad_t[row * 128 + ccb] = pk;
        }
    }
}

// ---- autocorr bf16 MFMA; 128-px blocks (16x8), 512 thr / 8 waves (2oh x 4pxg);
// full-K in block, direct store; 20 dbuf phases (T14) + T5 setprio
__global__ __launch_bounds__(512)
__attribute__((amdgpu_waves_per_eu(2, 2)))
void autocorr_mfma(const ushort* __restrict__ ft,
                   const short* __restrict__ wA,
                   const float* __restrict__ breg,
                   float* __restrict__ out) {
    __shared__ __align__(16) short flds[240 * 136];      // 12 x 20 halo px, 65.3 KB
    __shared__ __align__(16) short wlds[2][5 * 64 * 32]; // 41.0 KB
    const int tid = threadIdx.x;
    const int lane = tid & 63, wv = tid >> 6;
    const int oh = wv >> 2, pxg = wv & 3;
    const int j0 = blockIdx.x * 16, i0 = blockIdx.y * 8, b = blockIdx.z;
    const int l15 = lane & 15, kg = lane >> 4;

    int abase[2];
#pragma unroll
    for (int mm = 0; mm < 2; ++mm) {
        int o = oh * 32 + mm * 16 + l15;
        abase[mm] = o * 32 + ((((o >> 1) + kg) & 3) << 3);
    }
    // staging chunk maps: 1280 chunks over 512 threads (2.5/thread)
    int wdst[3]; int goff[3];
#pragma unroll
    for (int k = 0; k < 3; ++k) {
        int c = tid + k * 512;
        int o = (c & 255) >> 2, kgc = c & 3;
        wdst[k] = (c >> 8) * 2048 + o * 32 + ((((o >> 1) + kgc) & 3) << 3);
        goff[k] = c * 8;
    }
    const bool w3 = tid < 256;   // third chunk valid only for tid<256

    // prologue: f-tile (240 hpx x 16 segs = 3840 chunks) + w phase 0
    for (int e = tid; e < 3840; e += 512) {
        int hp = e >> 4, seg = e & 15;
        int hr = hp / 20, hc = hp - hr * 20;
        const ushort* src = ft + ((size_t)b * HPX_ + (i0 + hr) * HP_ + (j0 + hc)) * 128 + seg * 8;
        *(bh8*)&flds[hp * 136 + seg * 8] = *(const bh8*)src;
    }
    *(bh8*)&wlds[0][wdst[0]] = *(const bh8*)(wA + goff[0]);
    *(bh8*)&wlds[0][wdst[1]] = *(const bh8*)(wA + goff[1]);
    if (w3) *(bh8*)&wlds[0][wdst[2]] = *(const bh8*)(wA + goff[2]);
    __syncthreads();

    f4 acc[2][2] = {};
    int base_off[2], cen_off[2];
#pragma unroll
    for (int t = 0; t < 2; ++t) {
        int px = pxg * 32 + t * 16 + l15;
        int pi = px >> 4, pj = px & 15;
        base_off[t] = (pi * 20 + pj) * 136 + kg * 8;
        cen_off[t]  = ((pi + 2) * 20 + (pj + 2)) * 136 + kg * 8;
    }

    int p = 0;
#pragma unroll 1
    for (int q = 0; q < 4; ++q) {
        float cen[2][8];
#pragma unroll
        for (int t = 0; t < 2; ++t) {
            bh8 c8 = *(const bh8*)&flds[cen_off[t] + q * 32];
#pragma unroll
            for (int jj = 0; jj < 8; ++jj) cen[t][jj] = bf2f((ushort)c8[jj]);
        }
#pragma unroll 1
        for (int u = 0; u < 5; ++u) {
            const int buf = p & 1;
            const bool wmore = (p < 19);

            // 1. issue next-phase loads early
            bh8 wreg0, wreg1, wreg2;
            const short* gsrc = wA + (size_t)(wmore ? (p + 1) : 19) * 10240;
            wreg0 = *(const bh8*)(gsrc + goff[0]);
            wreg1 = *(const bh8*)(gsrc + goff[1]);
            if (w3) wreg2 = *(const bh8*)(gsrc + goff[2]);

            // 2. compute 5 v-steps from LDS only
            const short* wb = wlds[buf];
#pragma unroll
            for (int v = 0; v < 5; ++v) {
                const int koff = (u * 20 + v) * 136;
                bh8 a[2];
#pragma unroll
                for (int mm = 0; mm < 2; ++mm)
                    a[mm] = *(const bh8*)&wb[v * 2048 + abase[mm]];
                bh8 bb[2];
#pragma unroll
                for (int t = 0; t < 2; ++t) {
                    bh8 s8 = *(const bh8*)&flds[base_off[t] + q * 32 + koff];
#pragma unroll
                    for (int jj = 0; jj < 8; ++jj) {
                        float pr = bf2f((ushort)s8[jj]) * cen[t][jj];
                        bb[t][jj] = f2bf_c(pr);
                    }
                }
                __builtin_amdgcn_s_setprio(1);
#pragma unroll
                for (int mm = 0; mm < 2; ++mm)
#pragma unroll
                    for (int t = 0; t < 2; ++t)
                        acc[mm][t] = __builtin_amdgcn_mfma_f32_16x16x32_bf16(
                            a[mm], bb[t], acc[mm][t], 0, 0, 0);
                __builtin_amdgcn_s_setprio(0);
            }

            // 3. write-late
            if (wmore) {
                *(bh8*)&wlds[buf ^ 1][wdst[0]] = wreg0;
                *(bh8*)&wlds[buf ^ 1][wdst[1]] = wreg1;
                if (w3) *(bh8*)&wlds[buf ^ 1][wdst[2]] = wreg2;
            }
            __syncthreads();
            ++p;
        }
    }

    // epilogue: D row -> o, col -> px (16-wide tile)
#pragma unroll
    for (int mm = 0; mm < 2; ++mm) {
#pragma unroll
        for (int reg = 0; reg < 4; ++reg) {
            int o = oh * 32 + mm * 16 + kg * 4 + reg;
            float bv = breg[o];
#pragma unroll
            for (int t = 0; t < 2; ++t) {
                int px = pxg * 32 + t * 16 + l15, pi = px >> 4, pj = px & 15;
                out[(((size_t)(b * COUT_ + o)) * 64 + i0 + pi) * 64 + j0 + pj] =
                    acc[mm][t][reg] + bv;
            }
        }
    }
}

extern "C" void kernel_launch(void* const* d_in, const int* in_sizes, int n_in,
                              void* d_out, int out_size, void* d_ws, size_t ws_size,
                              hipStream_t stream) {
    const float* x     = (const float*)d_in[0];
    const float* w_ext = (const float*)d_in[1];
    const float* b_ext = (const float*)d_in[2];
    const float* w_reg = (const float*)d_in[3];
    const float* b_reg = (const float*)d_in[4];
    float* out = (float*)d_out;

    char* ws = (char*)d_ws;
    const size_t FPADT_BYTES = (size_t)B_ * HPX_ * 128 * 2;
    const size_t WG_BYTES    = (size_t)8 * 9 * 128 * 32 * 2;
    const size_t WA_BYTES    = (size_t)4 * 25 * 64 * 32 * 2;
    ushort* fpad_t = (ushort*)ws;
    short*  wgq    = (short*)(ws + FPADT_BYTES);
    short*  wa     = (short*)(ws + FPADT_BYTES + WG_BYTES);
    ushort* xq     = (ushort*)(ws + FPADT_BYTES + WG_BYTES + WA_BYTES);

    prep_all<<<NB_MISC + 33 * 8 * 8, 256, 0, stream>>>(x, w_ext, w_reg, wgq, wa, fpad_t, xq);

    dim3 cgrid(8, 8, 8);
    conv3x3_mfma<<<cgrid, 256, 0, stream>>>(xq, wgq, b_ext, fpad_t);
    dim3 agrid(4, 8, 8);
    autocorr_mfma<<<agrid, 512, 0, stream>>>(fpad_t, wa, b_reg, out);
}

// Round 21
// 72.771 us; speedup vs baseline: 1.0890x; 1.0161x over previous
//
#include <hip/hip_runtime.h>
#include <hip/hip_bf16.h>

#define B_    8
#define CIN_  256
#define CC_   128
#define COUT_ 64
#define HP_   68            // f padded: 64 + 2 + 2
#define HPX_  (HP_ * HP_)   // 4624
#define XQW_  66            // x padded: 64 + 1 + 1
#define XQPX_ (XQW_ * XQW_) // 4356

typedef __attribute__((ext_vector_type(8))) short bh8;
typedef __attribute__((ext_vector_type(4))) float f4;

__device__ __forceinline__ ushort f2bf(float f) {   // RNE
    uint u = __float_as_uint(f);
    return (ushort)((u + 0x7fffu + ((u >> 16) & 1u)) >> 16);
}
__device__ __forceinline__ float bf2f(ushort s) {
    return __uint_as_float(((uint)s) << 16);
}
__device__ __forceinline__ short f2bf_c(float f) {
    __hip_bfloat16 h = __float2bfloat16(f);
    short s;
    __builtin_memcpy(&s, &h, 2);
    return s;
}

// ---- merged prep: ring-zero + weight transforms + x transpose/quantize
#define NB_MISC 2217
__global__ __launch_bounds__(256) void prep_all(const float* __restrict__ x,
                                                const float* __restrict__ w_ext,
                                                const float* __restrict__ w_reg,
                                                short* __restrict__ wg,
                                                short* __restrict__ wa,
                                                ushort* __restrict__ fpad_t,
                                                ushort* __restrict__ xq) {
    __shared__ float xt[2][32][65];
    const int tid = threadIdx.x;
    if (blockIdx.x < NB_MISC) {
        int e = blockIdx.x * 256 + tid;
        if (e < 67584) {
            int seg = e & 15;
            int t = e >> 4;
            int b = t / 528, rp = t - b * 528;
            int i, j;
            if (rp < 136) { i = rp / 68; j = rp - (rp / 68) * 68; }
            else if (rp < 272) { int r = rp - 136; i = 66 + r / 68; j = r - (r / 68) * 68; }
            else { int r = rp - 272; i = 2 + (r >> 2); int c = r & 3; j = (c < 2) ? c : c + 64; }
            uint4 z; z.x = 0u; z.y = 0u; z.z = 0u; z.w = 0u;
            *(uint4*)&fpad_t[(((size_t)b * HPX_) + i * HP_ + j) * 128 + seg * 8] = z;
            return;
        }
        e -= 67584;
        if (e < 294912) {
            int ci = e & 31;
            int t  = e >> 5;
            int cc = t & 127;
            int t2 = t >> 7;
            int rs = t2 % 9, cb = t2 / 9;
            wg[e] = (short)f2bf(w_ext[(cc * CIN_ + cb * 32 + ci) * 9 + rs]);
            return;
        }
        e -= 294912;
        if (e < 204800) {
            int ci = e & 31;
            int o  = (e >> 5) & 63;
            int rest = e >> 11;
            int k = rest % 25, q = rest / 25;
            wa[e] = (short)f2bf(w_reg[(o * CC_ + q * 32 + ci) * 25 + k]);
        }
        return;
    }

    const int pid = blockIdx.x - NB_MISC;
    const int rp = pid % 33, cb = (pid / 33) & 7, b = pid / 264;

#pragma unroll
    for (int rr = 0; rr < 2; ++rr) {
        int y = rp * 2 + rr - 1;
        if ((unsigned)y < 64u) {
            int xx = tid & 63, wv = tid >> 6;
#pragma unroll
            for (int it = 0; it < 8; ++it) {
                int ci = it * 4 + wv;
                xt[rr][ci][xx] = x[(((size_t)(b * CIN_ + cb * 32 + ci)) * 64 + y) * 64 + xx];
            }
        }
    }
    __syncthreads();

    for (int e = tid; e < 528; e += 256) {
        int rr = e / 264, t = e - rr * 264;
        int hc = t >> 2, seg = t & 3;
        int y = rp * 2 + rr - 1, xx = hc - 1;
        uint pk[4] = {0u, 0u, 0u, 0u};
        if ((unsigned)y < 64u && (unsigned)xx < 64u) {
#pragma unroll
            for (int i = 0; i < 4; ++i) {
                uint lo = f2bf(xt[rr][seg * 8 + i * 2][xx]);
                uint hi = f2bf(xt[rr][seg * 8 + i * 2 + 1][xx]);
                pk[i] = lo | (hi << 16);
            }
        }
        uint4 v; v.x = pk[0]; v.y = pk[1]; v.z = pk[2]; v.w = pk[3];
        *(uint4*)&xq[((((size_t)(b * 8 + cb)) * XQPX_) + (rp * 2 + rr) * XQW_ + hc) * 32 + seg * 8] = v;
    }
}

// ---- conv 3x3 bf16 MFMA; 8x8 tile, 256 thr / 4 waves (r20 best, unchanged)
__global__ __launch_bounds__(256)
__attribute__((amdgpu_waves_per_eu(2, 2)))
void conv3x3_mfma(const ushort* __restrict__ xq,
                  const short* __restrict__ wg,
                  const float* __restrict__ bext,
                  ushort* __restrict__ fpad_t) {
    __shared__ __align__(16) short xh[2][100 * 72];
    __shared__ __align__(16) short wlds[2][3 * 128 * 32];
    const int tid = threadIdx.x;
    const int lane = tid & 63, wv = tid >> 6;
    const int j0 = blockIdx.x * 8, i0 = blockIdx.y * 8, b = blockIdx.z;
    const int l15 = lane & 15, kg = lane >> 4;
    const int cc0 = wv * 32;

    int abase[2];
#pragma unroll
    for (int mm = 0; mm < 2; ++mm) {
        int cc = cc0 + mm * 16 + l15;
        abase[mm] = cc * 32 + ((((cc >> 1) + kg) & 3) << 3);
    }
    int xb[4];
#pragma unroll
    for (int nn = 0; nn < 4; ++nn) {
        int px = nn * 16 + l15, pi = px >> 3, pj = px & 7;
        xb[nn] = (pi * 10 + pj) * 72 + kg * 8;
    }
    int wdst[6]; int goff[6];
#pragma unroll
    for (int k = 0; k < 6; ++k) {
        int c = tid + k * 256;
        int cc = (c & 511) >> 2, kgc = c & 3;
        wdst[k] = (c >> 9) * 4096 + cc * 32 + ((((cc >> 1) + kgc) & 3) << 3);
        goff[k] = c * 8;
    }
    const int hp0 = tid >> 2, seg0 = tid & 3;
    const int hr0 = hp0 / 10, hc0 = hp0 - hr0 * 10;
    const int xsrc0 = ((i0 + hr0) * XQW_ + (j0 + hc0)) * 32 + seg0 * 8;
    const int xdst0 = hp0 * 72 + seg0 * 8;
    const int hp1 = (tid + 256) >> 2;
    const int hr1 = hp1 / 10, hc1 = hp1 - hr1 * 10;
    const int xsrc1 = ((i0 + hr1) * XQW_ + (j0 + hc1)) * 32 + seg0 * 8;
    const int xdst1 = hp1 * 72 + seg0 * 8;
    const bool x1ok = tid < 144;

    f4 acc[2][4] = {};

    {
#pragma unroll
        for (int k = 0; k < 6; ++k)
            *(bh8*)&wlds[0][wdst[k]] = *(const bh8*)(wg + goff[k]);
        const ushort* xbase = xq + (((size_t)(b * 8 + 0)) * XQPX_) * 32;
        *(bh8*)&xh[0][xdst0] = *(const bh8*)&xbase[xsrc0];
        if (x1ok) *(bh8*)&xh[0][xdst1] = *(const bh8*)&xbase[xsrc1];
    }
    __syncthreads();

    int p = 0;
#pragma unroll 1
    for (int cb = 0; cb < 8; ++cb) {
        const int xbuf = cb & 1;
#pragma unroll 1
        for (int g = 0; g < 3; ++g) {
            const int buf = p & 1;
            const bool wmore = (p < 23);
            const bool xmore = (g == 2) && (cb < 7);

            bh8 wreg[6];
            const short* gsrc = wg + (size_t)(wmore ? (p + 1) : 23) * 12288;
#pragma unroll
            for (int k = 0; k < 6; ++k)
                wreg[k] = *(const bh8*)(gsrc + goff[k]);
            bh8 xr0, xr1;
            if (xmore) {
                const ushort* xbase = xq + (((size_t)(b * 8 + cb + 1)) * XQPX_) * 32;
                xr0 = *(const bh8*)&xbase[xsrc0];
                if (x1ok) xr1 = *(const bh8*)&xbase[xsrc1];
            }

            const short* wb = wlds[buf];
            const int goffs = g * 10 * 72;
#pragma unroll
            for (int s = 0; s < 3; ++s) {
                bh8 a[2], bb[4];
#pragma unroll
                for (int mm = 0; mm < 2; ++mm)
                    a[mm] = *(const bh8*)&wb[s * 4096 + abase[mm]];
#pragma unroll
                for (int nn = 0; nn < 4; ++nn)
                    bb[nn] = *(const bh8*)&xh[xbuf][xb[nn] + goffs + s * 72];
                __builtin_amdgcn_s_setprio(1);
#pragma unroll
                for (int mm = 0; mm < 2; ++mm)
#pragma unroll
                    for (int nn = 0; nn < 4; ++nn)
                        acc[mm][nn] = __builtin_amdgcn_mfma_f32_16x16x32_bf16(
                            a[mm], bb[nn], acc[mm][nn], 0, 0, 0);
                __builtin_amdgcn_s_setprio(0);
            }

            if (wmore) {
#pragma unroll
                for (int k = 0; k < 6; ++k)
                    *(bh8*)&wlds[buf ^ 1][wdst[k]] = wreg[k];
            }
            if (xmore) {
                *(bh8*)&xh[xbuf ^ 1][xdst0] = xr0;
                if (x1ok) *(bh8*)&xh[xbuf ^ 1][xdst1] = xr1;
            }
            __syncthreads();
            ++p;
        }
    }

#pragma unroll
    for (int mm = 0; mm < 2; ++mm) {
        const int ccb = cc0 + mm * 16 + kg * 4;
        float bv0 = bext[ccb + 0], bv1 = bext[ccb + 1];
        float bv2 = bext[ccb + 2], bv3 = bext[ccb + 3];
#pragma unroll
        for (int nn = 0; nn < 4; ++nn) {
            int px = nn * 16 + l15, pi = px >> 3, pj = px & 7;
            size_t row = (size_t)b * HPX_ + (2 + i0 + pi) * HP_ + (2 + j0 + pj);
            uint lo = (uint)f2bf(acc[mm][nn][0] + bv0) | ((uint)f2bf(acc[mm][nn][1] + bv1) << 16);
            uint hi = (uint)f2bf(acc[mm][nn][2] + bv2) | ((uint)f2bf(acc[mm][nn][3] + bv3) << 16);
            uint2 pk; pk.x = lo; pk.y = hi;
            *(uint2*)&fpad_t[row * 128 + ccb] = pk;
        }
    }
}

// ---- autocorr bf16 MFMA v21; 8x8 tile, 256 thr / 4 waves, wave = 64o x 16px
// (m=4, n=1): bb built EXACTLY ONCE per px (no oh duplication -> VALU halved).
// flds 39.2 KB + wlds dbuf 41 KB = 80.1 KB -> 2 blocks/CU. 20 dbuf phases,
// issue-early/write-late, direct store.
__global__ __launch_bounds__(256)
__attribute__((amdgpu_waves_per_eu(2, 2)))
void autocorr_mfma(const ushort* __restrict__ ft,
                   const short* __restrict__ wA,
                   const float* __restrict__ breg,
                   float* __restrict__ out) {
    __shared__ __align__(16) short flds[144 * 136];      // 12x12 halo px, 39.2 KB
    __shared__ __align__(16) short wlds[2][5 * 64 * 32]; // 41.0 KB
    const int tid = threadIdx.x;
    const int lane = tid & 63, wv = tid >> 6;            // 4 waves, split px
    const int j0 = blockIdx.x * 8, i0 = blockIdx.y * 8, b = blockIdx.z;
    const int l15 = lane & 15, kg = lane >> 4;

    int abase[4];
#pragma unroll
    for (int mm = 0; mm < 4; ++mm) {
        int o = mm * 16 + l15;
        abase[mm] = o * 32 + ((((o >> 1) + kg) & 3) << 3);
    }
    // w staging: 1280 chunks over 256 threads = 5 exact
    int wdst[5]; int goff[5];
#pragma unroll
    for (int k = 0; k < 5; ++k) {
        int c = tid + k * 256;
        int o = (c & 255) >> 2, kgc = c & 3;
        wdst[k] = (c >> 8) * 2048 + o * 32 + ((((o >> 1) + kgc) & 3) << 3);
        goff[k] = c * 8;
    }

    // prologue: f-tile (144 hpx x 16 segs = 2304 chunks) + w phase 0
    for (int e = tid; e < 2304; e += 256) {
        int hp = e >> 4, seg = e & 15;
        int hr = hp / 12, hc = hp - hr * 12;
        const ushort* src = ft + ((size_t)b * HPX_ + (i0 + hr) * HP_ + (j0 + hc)) * 128 + seg * 8;
        *(bh8*)&flds[hp * 136 + seg * 8] = *(const bh8*)src;
    }
#pragma unroll
    for (int k = 0; k < 5; ++k)
        *(bh8*)&wlds[0][wdst[k]] = *(const bh8*)(wA + goff[k]);
    __syncthreads();

    f4 acc[4] = {};
    const int px = wv * 16 + l15, pi = px >> 3, pj = px & 7;
    const int base_off = (pi * 12 + pj) * 136 + kg * 8;
    const int cen_off  = ((pi + 2) * 12 + (pj + 2)) * 136 + kg * 8;

    int p = 0;
#pragma unroll 1
    for (int q = 0; q < 4; ++q) {
        bh8 c8 = *(const bh8*)&flds[cen_off + q * 32];
        float cen[8];
#pragma unroll
        for (int jj = 0; jj < 8; ++jj) cen[jj] = bf2f((ushort)c8[jj]);

#pragma unroll 1
        for (int u = 0; u < 5; ++u) {
            const int buf = p & 1;
            const bool wmore = (p < 19);

            // 1. issue next-phase loads early
            bh8 wreg[5];
            const short* gsrc = wA + (size_t)(wmore ? (p + 1) : 19) * 10240;
#pragma unroll
            for (int k = 0; k < 5; ++k)
                wreg[k] = *(const bh8*)(gsrc + goff[k]);

            // 2. compute 5 v-steps from LDS only (bb once, 4 MFMA each)
            const short* wb = wlds[buf];
#pragma unroll
            for (int v = 0; v < 5; ++v) {
                const int koff = (u * 12 + v) * 136;
                bh8 a[4];
#pragma unroll
                for (int mm = 0; mm < 4; ++mm)
                    a[mm] = *(const bh8*)&wb[v * 2048 + abase[mm]];
                bh8 s8 = *(const bh8*)&flds[base_off + q * 32 + koff];
                bh8 bb;
#pragma unroll
                for (int jj = 0; jj < 8; ++jj)
                    bb[jj] = f2bf_c(bf2f((ushort)s8[jj]) * cen[jj]);
                __builtin_amdgcn_s_setprio(1);
#pragma unroll
                for (int mm = 0; mm < 4; ++mm)
                    acc[mm] = __builtin_amdgcn_mfma_f32_16x16x32_bf16(
                        a[mm], bb, acc[mm], 0, 0, 0);
                __builtin_amdgcn_s_setprio(0);
            }

            // 3. write-late
            if (wmore) {
#pragma unroll
                for (int k = 0; k < 5; ++k)
                    *(bh8*)&wlds[buf ^ 1][wdst[k]] = wreg[k];
            }
            __syncthreads();
            ++p;
        }
    }

    // epilogue: D row -> o, col -> px; direct store + bias
#pragma unroll
    for (int mm = 0; mm < 4; ++mm) {
#pragma unroll
        for (int reg = 0; reg < 4; ++reg) {
            int o = mm * 16 + kg * 4 + reg;
            out[(((size_t)(b * COUT_ + o)) * 64 + i0 + pi) * 64 + j0 + pj] =
                acc[mm][reg] + breg[o];
        }
    }
}

extern "C" void kernel_launch(void* const* d_in, const int* in_sizes, int n_in,
                              void* d_out, int out_size, void* d_ws, size_t ws_size,
                              hipStream_t stream) {
    const float* x     = (const float*)d_in[0];
    const float* w_ext = (const float*)d_in[1];
    const float* b_ext = (const float*)d_in[2];
    const float* w_reg = (const float*)d_in[3];
    const float* b_reg = (const float*)d_in[4];
    float* out = (float*)d_out;

    char* ws = (char*)d_ws;
    const size_t FPADT_BYTES = (size_t)B_ * HPX_ * 128 * 2;
    const size_t WG_BYTES    = (size_t)8 * 9 * 128 * 32 * 2;
    const size_t WA_BYTES    = (size_t)4 * 25 * 64 * 32 * 2;
    ushort* fpad_t = (ushort*)ws;
    short*  wgq    = (short*)(ws + FPADT_BYTES);
    short*  wa     = (short*)(ws + FPADT_BYTES + WG_BYTES);
    ushort* xq     = (ushort*)(ws + FPADT_BYTES + WG_BYTES + WA_BYTES);

    prep_all<<<NB_MISC + 33 * 8 * 8, 256, 0, stream>>>(x, w_ext, w_reg, wgq, wa, fpad_t, xq);

    dim3 cgrid(8, 8, 8);
    conv3x3_mfma<<<cgrid, 256, 0, stream>>>(xq, wgq, b_ext, fpad_t);
    dim3 agrid(8, 8, 8);
    autocorr_mfma<<<agrid, 256, 0, stream>>>(fpad_t, wa, b_reg, out);
}